// Round 1
// baseline (174.931 us; speedup 1.0000x reference)
//
#include <hip/hip_runtime.h>
#include <hip/hip_bf16.h>

typedef __attribute__((ext_vector_type(8)))  short  short8;
typedef __attribute__((ext_vector_type(16))) float  floatx16;

#define N_ROWS   16384
#define IN_DIM   512
#define OUT_DIM  512
#define K_SPLINE 4096
#define K_TOT    4608
#define NKT16    288            /* 16-k B tiles total (4608/16) */
#define NKT64    72             /* 64-k halves */
#define NPER     36             /* 128-k barrier periods */
#define NSPER    32             /* spline periods (4096/128) */
#define NCT      16             /* 32-col B groups (512/32) */
#define L2E      1.4426950408889634f
#define C2E      0.13533528323661270f   /* exp(-2) */

__device__ __forceinline__ unsigned short f2bf(float f) {
    unsigned int u = __float_as_uint(f);
    unsigned int r = u + 0x7FFFu + ((u >> 16) & 1u);
    return (unsigned short)(r >> 16);
}

// truncating pack: two fp32 -> two bf16 in one v_perm_b32 (A-side only; B rounded in prep)
__device__ __forceinline__ unsigned packtrunc(float f0, float f1) {
    return __builtin_amdgcn_perm(__float_as_uint(f1), __float_as_uint(f0), 0x07060302);
}

// ---------------------------------------------------------------------------
// prep: B in 32x32x16 MFMA B-fragment-tiled layout.
// frag idx = (ct*NKT16 + kt16)*64 + lane ; elem j:
//   n = ct*32 + (lane&31), k = kt16*16 + (lane>>5)*8 + j
// ---------------------------------------------------------------------------
__global__ __launch_bounds__(256) void prep_kernel(
    const float* __restrict__ sw, const float* __restrict__ bw,
    unsigned short* __restrict__ Btf)
{
    const int t    = threadIdx.x;
    const int lane = t & 63;
    const int kt16 = blockIdx.x * 4 + (t >> 6);   // grid.x = 72
    const int ct   = blockIdx.y;                  // 16
    const int n    = ct * 32 + (lane & 31);
    const int kb   = kt16 * 16 + (lane >> 5) * 8;
    short8 v;
    if (kb < K_SPLINE) {
        #pragma unroll
        for (int j = 0; j < 8; ++j)
            v[j] = (short)f2bf(sw[(size_t)(kb + j) * OUT_DIM + n]);
    } else {
        #pragma unroll
        for (int j = 0; j < 8; ++j)
            v[j] = (short)f2bf(bw[(size_t)n * IN_DIM + (kb + j - K_SPLINE)]);
    }
    reinterpret_cast<short8*>(Btf)[(size_t)(ct * NKT16 + kt16) * 64 + lane] = v;
}

// ---------------------------------------------------------------------------
// 8 basis values of one x -> packed uint4 (bf16 x8)
// v[j] = exp(-(u-j)^2), u = (x+2)/h, h=4/7 -> u = 1.75x + 3.5
// ---------------------------------------------------------------------------
__device__ __forceinline__ uint4 basis_pack(float X) {
    const float u = fmaf(1.75f, X, 3.5f);
    float b = __builtin_amdgcn_exp2f(-(u * u) * L2E);            // exp(-u^2)
    float r = __builtin_amdgcn_exp2f(fmaf(2.0f * L2E, u, -L2E)); // exp(2u-1)
    float v[8];
    v[0] = b;
    #pragma unroll
    for (int j = 1; j < 8; ++j) { b *= r; r *= C2E; v[j] = b; }
    uint4 p;
    p.x = packtrunc(v[0], v[1]);
    p.y = packtrunc(v[2], v[3]);
    p.z = packtrunc(v[4], v[5]);
    p.w = packtrunc(v[6], v[7]);
    return p;
}

// One 16B staging slice (e-block) into swizzled LDS row.
// A LDS: 64 rows x 128 k ushort; 16B blocks, stored blk = kb ^ (row&15).
__device__ __forceinline__ void stage_spl_e(unsigned short* arow, int rowA, int colq,
                                            float X, int e)
{
    const uint4 pk = basis_pack(X);
    const int blk = (colq * 4 + e) ^ (rowA & 15);
    *reinterpret_cast<uint4*>(arow + blk * 8) = pk;
}

__device__ __forceinline__ void stage_silu_e(unsigned short* arow, const float* xs,
                                             int rowA, int colq, int e)
{
    const float4 a0 = *reinterpret_cast<const float4*>(xs + e * 8);
    const float4 a1 = *reinterpret_cast<const float4*>(xs + e * 8 + 4);
    const float f[8] = {a0.x, a0.y, a0.z, a0.w, a1.x, a1.y, a1.z, a1.w};
    float sv[8];
    #pragma unroll
    for (int j = 0; j < 8; ++j)
        sv[j] = f[j] * __builtin_amdgcn_rcpf(
            1.0f + __builtin_amdgcn_exp2f(-f[j] * L2E));
    uint4 pk;
    pk.x = packtrunc(sv[0], sv[1]);
    pk.y = packtrunc(sv[2], sv[3]);
    pk.z = packtrunc(sv[4], sv[5]);
    pk.w = packtrunc(sv[6], sv[7]);
    const int blk = (colq * 4 + e) ^ (rowA & 15);
    *reinterpret_cast<uint4*>(arow + blk * 8) = pk;
}

// B fragments for one 64-k half (4 x 16-k steps, 2 col groups). No bounds
// branch: every call site is provably in range (kt64 <= 71).
template<bool PREP>
__device__ __forceinline__ void load_bhalf(short8 dst[2][4], const short8* __restrict__ Bf,
                                           const unsigned* boff, int kt64,
                                           const float* __restrict__ sw,
                                           const float* __restrict__ bw,
                                           int col0, int lane)
{
    if (PREP) {
        #pragma unroll
        for (int nt = 0; nt < 2; ++nt)
            #pragma unroll
            for (int s = 0; s < 4; ++s)
                dst[nt][s] = Bf[boff[nt] + (unsigned)(kt64 * 4 + s) * 64u];
    } else {
        #pragma unroll
        for (int nt = 0; nt < 2; ++nt) {
            const int n = col0 + nt * 32 + (lane & 31);
            #pragma unroll
            for (int s = 0; s < 4; ++s) {
                const int kb = (kt64 * 4 + s) * 16 + (lane >> 5) * 8;
                short8 v;
                #pragma unroll
                for (int j = 0; j < 8; ++j) {
                    const int k = kb + j;
                    const float val = (k < K_SPLINE)
                        ? sw[(size_t)k * OUT_DIM + n]
                        : bw[(size_t)n * IN_DIM + (k - K_SPLINE)];
                    v[j] = (short)f2bf(val);
                }
                dst[nt][s] = v;
            }
        }
    }
}

// ---------------------------------------------------------------------------
// One 128-k period, fully straight-line (single BB between barriers) so the
// scheduler can interleave staging VALU / B loads / A ds_reads with MFMAs.
// MODE: 0 = stage spline tile p+1, 1 = stage silu tile p+1, 2 = no staging.
// 8 x 16-k steps; A-frag dbuf one step ahead; 4 x mfma_32x32x16 per step.
// ---------------------------------------------------------------------------
template<int MODE, bool PREP>
__device__ __forceinline__ void period_body(
    int p,
    const unsigned short* __restrict__ Acur,
    unsigned short* __restrict__ anrow,          // Anxt + rowA*128
    short8 bb[2][2][4], floatx16 acc[2][2],
    const int aoff[2][8],
    const unsigned* boff, const short8* __restrict__ Bf,
    float4& xsp, const float* __restrict__ xrow, int rowA, int colq,
    const float* __restrict__ sw, const float* __restrict__ bw,
    int col0, int lane)
{
    const float xv[4] = {xsp.x, xsp.y, xsp.z, xsp.w};
    const float* xs = (MODE == 1) ? (xrow + (p + 1 - NSPER) * 128 + colq * 32)
                                  : xrow;

    short8 af[2][2];
    #pragma unroll
    for (int mt = 0; mt < 2; ++mt)
        af[0][mt] = *reinterpret_cast<const short8*>(Acur + aoff[mt][0]);

    #pragma unroll
    for (int st = 0; st < 8; ++st) {
        const int hh = st >> 2, s = st & 3, cb = st & 1;
        if (st < 7) {
            #pragma unroll
            for (int mt = 0; mt < 2; ++mt)
                af[cb ^ 1][mt] = *reinterpret_cast<const short8*>(
                    Acur + aoff[mt][st + 1]);
        }
        if (MODE == 0 && st < 4) stage_spl_e(anrow, rowA, colq, xv[st], st);
        if (MODE == 1 && st < 4) stage_silu_e(anrow, xs, rowA, colq, st);
        if (st == 0)
            load_bhalf<PREP>(bb[1], Bf, boff, 2 * p + 1, sw, bw, col0, lane);
        if (MODE != 2 && st == 4)
            load_bhalf<PREP>(bb[0], Bf, boff, 2 * p + 2, sw, bw, col0, lane);
        if (MODE == 0 && st == 3) {
            const int pp = (p + 2 < NSPER) ? p + 2 : NSPER - 1;
            xsp = *reinterpret_cast<const float4*>(xrow + pp * 16 + colq * 4);
        }
        __builtin_amdgcn_s_setprio(1);
        #pragma unroll
        for (int mt = 0; mt < 2; ++mt)
            #pragma unroll
            for (int nt = 0; nt < 2; ++nt)
                acc[mt][nt] = __builtin_amdgcn_mfma_f32_32x32x16_bf16(
                    af[cb][mt], bb[hh][nt][s], acc[mt][nt], 0, 0, 0);
        __builtin_amdgcn_s_setprio(0);
    }
    __syncthreads();
}

// ---------------------------------------------------------------------------
// Fused KAN, 32x32x16 MFMA edition.
//   512 blocks x 4 waves; block tile 64x256; wave tile 64x64 (2x2 32x32 frags)
//   A LDS dbuf 2x16KB (layout unchanged); B reg dbuf 64-k halves.
//   p-loop split by staging mode so each period body is one basic block.
// ---------------------------------------------------------------------------
template<bool PREP>
__global__ __launch_bounds__(256, 2) void kan_kernel(
    const float* __restrict__ x,
    const unsigned short* __restrict__ Btf,
    const float* __restrict__ sw,
    const float* __restrict__ bw,
    const float* __restrict__ bias,
    float* __restrict__ out)
{
    __shared__ unsigned short Als[2][64 * 128];   // 2 x 16 KB

    const int tid  = threadIdx.x;
    const int wn   = tid >> 6;
    const int lane = tid & 63;
    const int h    = lane >> 5;
    const int mn   = lane & 31;
    const int bid  = blockIdx.x;
    const int row0 = (bid >> 1) * 64;
    const int col0 = (bid & 1) * 256 + wn * 64;   // bid&1: XCD-parity col half

    const int rowA = tid >> 2;                    // 0..63
    const int colq = tid & 3;
    const float* xrow = x + (size_t)(row0 + rowA) * IN_DIM;

    unsigned boff[2];
    #pragma unroll
    for (int nt = 0; nt < 2; ++nt)
        boff[nt] = (unsigned)(((col0 >> 5) + nt) * NKT16) * 64u + (unsigned)lane;
    const short8* Bf = reinterpret_cast<const short8*>(Btf);

    // A ds_read offsets (ushort units), loop-invariant: 2 mt x 8 st.
    // row r = mt*32 + (lane&31); 16B block (st*2 + h) ^ (r&15).
    int aoff[2][8];
    #pragma unroll
    for (int mt = 0; mt < 2; ++mt) {
        const int r = mt * 32 + mn;
        #pragma unroll
        for (int st = 0; st < 8; ++st)
            aoff[mt][st] = r * 128 + (((st * 2 + h) ^ (r & 15)) * 8);
    }

    floatx16 acc[2][2];
    #pragma unroll
    for (int i = 0; i < 2; ++i)
        #pragma unroll
        for (int j = 0; j < 2; ++j)
            #pragma unroll
            for (int e = 0; e < 16; ++e)
                acc[i][j][e] = 0.f;

    short8 bb[2][2][4];

    // prologue: stage tile 0, B for kt64=0, prefetch spline x for tile 1
    float4 xsp = *reinterpret_cast<const float4*>(xrow + colq * 4);
    {
        unsigned short* arow0 = &Als[0][0] + rowA * 128;
        const float xv0[4] = {xsp.x, xsp.y, xsp.z, xsp.w};
        #pragma unroll
        for (int e = 0; e < 4; ++e)
            stage_spl_e(arow0, rowA, colq, xv0[e], e);
    }
    load_bhalf<PREP>(bb[0], Bf, boff, 0, sw, bw, col0, lane);
    xsp = *reinterpret_cast<const float4*>(xrow + 16 + colq * 4);
    __syncthreads();

    #pragma unroll 1
    for (int p = 0; p < NSPER - 1; ++p)           // 0..30: spline staging
        period_body<0, PREP>(p, &Als[p & 1][0],
                             &Als[(p & 1) ^ 1][0] + rowA * 128,
                             bb, acc, aoff, boff, Bf, xsp, xrow, rowA, colq,
                             sw, bw, col0, lane);
    #pragma unroll 1
    for (int p = NSPER - 1; p < NPER - 1; ++p)    // 31..34: silu staging
        period_body<1, PREP>(p, &Als[p & 1][0],
                             &Als[(p & 1) ^ 1][0] + rowA * 128,
                             bb, acc, aoff, boff, Bf, xsp, xrow, rowA, colq,
                             sw, bw, col0, lane);
    period_body<2, PREP>(NPER - 1, &Als[(NPER - 1) & 1][0],
                         &Als[0][0] + rowA * 128,
                         bb, acc, aoff, boff, Bf, xsp, xrow, rowA, colq,
                         sw, bw, col0, lane);

    // epilogue: + bias, store fp32.
    // 32x32x16 C/D: col = lane&31, row = (e&3) + 8*(e>>2) + 4*(lane>>5)
    #pragma unroll
    for (int nt = 0; nt < 2; ++nt) {
        const int col = col0 + nt * 32 + mn;
        const float bv = bias[col];
        #pragma unroll
        for (int mt = 0; mt < 2; ++mt) {
            #pragma unroll
            for (int e = 0; e < 16; ++e) {
                const int row = row0 + mt * 32 + (e & 3) + 8 * (e >> 2) + 4 * h;
                out[(size_t)row * OUT_DIM + col] = acc[mt][nt][e] + bv;
            }
        }
    }
}

extern "C" void kernel_launch(void* const* d_in, const int* in_sizes, int n_in,
                              void* d_out, int out_size, void* d_ws, size_t ws_size,
                              hipStream_t stream)
{
    const float* x    = (const float*)d_in[0];
    // d_in[1] = grid (linspace(-2,2,8)) — folded into constants
    const float* sw   = (const float*)d_in[2];
    const float* bw   = (const float*)d_in[3];
    const float* bias = (const float*)d_in[4];
    float* out = (float*)d_out;

    const size_t bt_bytes = (size_t)OUT_DIM * K_TOT * sizeof(unsigned short);
    if (ws_size >= bt_bytes) {
        unsigned short* Btf = (unsigned short*)d_ws;
        prep_kernel<<<dim3(NKT16 / 4, NCT), 256, 0, stream>>>(sw, bw, Btf);
        kan_kernel<true><<<dim3(512), 256, 0, stream>>>(
            x, Btf, sw, bw, bias, out);
    } else {
        kan_kernel<false><<<dim3(512), 256, 0, stream>>>(
            x, nullptr, sw, bw, bias, out);
    }
}

// Round 2
// 156.569 us; speedup vs baseline: 1.1173x; 1.1173x over previous
//
#include <hip/hip_runtime.h>
#include <hip/hip_bf16.h>

typedef __attribute__((ext_vector_type(8))) short short8;
typedef __attribute__((ext_vector_type(4))) float floatx4;

#define N_ROWS   16384
#define IN_DIM   512
#define OUT_DIM  512
#define K_SPLINE 4096
#define K_TOT    4608
#define NKT      72              /* 64-k half-periods  */
#define NPER     36              /* 128-k barrier periods */
#define NSPER    32              /* spline periods (4096/128) */
#define NKTILE   144             /* 32-wide k-tiles */
#define L2E      1.4426950408889634f
#define C2E      0.13533528323661270f   /* exp(-2) */

__device__ __forceinline__ unsigned short f2bf(float f) {
    unsigned int u = __float_as_uint(f);
    unsigned int r = u + 0x7FFFu + ((u >> 16) & 1u);
    return (unsigned short)(r >> 16);
}

// truncating pack: two fp32 -> two bf16 in one v_perm_b32 (A-side only; B rounded in prep)
__device__ __forceinline__ unsigned packtrunc(float f0, float f1) {
    return __builtin_amdgcn_perm(__float_as_uint(f1), __float_as_uint(f0), 0x07060302);
}

// ---------------------------------------------------------------------------
// prep: B in MFMA B-fragment-tiled layout (16x16x32).
// frag idx = (ct*NKTILE + kt32)*64 + lane ; elem j:
//   n = ct*16 + (lane&15), k = kt32*32 + (lane>>4)*8 + j
// ---------------------------------------------------------------------------
__global__ __launch_bounds__(256) void prep_kernel(
    const float* __restrict__ sw, const float* __restrict__ bw,
    unsigned short* __restrict__ Btf)
{
    const int t     = threadIdx.x;
    const int lane  = t & 63;
    const int kt32  = blockIdx.x * 4 + (t >> 6);
    const int ct    = blockIdx.y;
    const int mn    = lane & 15, q = lane >> 4;
    const int n     = ct * 16 + mn;
    const int kbase = kt32 * 32 + q * 8;
    short8 v;
    if (kbase < K_SPLINE) {
        #pragma unroll
        for (int j = 0; j < 8; ++j)
            v[j] = (short)f2bf(sw[(size_t)(kbase + j) * OUT_DIM + n]);
    } else {
        #pragma unroll
        for (int j = 0; j < 8; ++j)
            v[j] = (short)f2bf(bw[(size_t)n * IN_DIM + (kbase + j - K_SPLINE)]);
    }
    reinterpret_cast<short8*>(Btf)[(size_t)(ct * NKTILE + kt32) * 64 + lane] = v;
}

// ---------------------------------------------------------------------------
// 8 basis values of one x -> packed uint4 (bf16 x8)
// ---------------------------------------------------------------------------
__device__ __forceinline__ uint4 basis_pack(float X) {
    const float u = fmaf(1.75f, X, 3.5f);
    float b = __builtin_amdgcn_exp2f(-(u * u) * L2E);            // exp(-u^2)
    float r = __builtin_amdgcn_exp2f(fmaf(2.0f * L2E, u, -L2E)); // exp(2u-1)
    float v[8];
    v[0] = b;
    #pragma unroll
    for (int j = 1; j < 8; ++j) { b *= r; r *= C2E; v[j] = b; }
    uint4 p;
    p.x = packtrunc(v[0], v[1]);
    p.y = packtrunc(v[2], v[3]);
    p.z = packtrunc(v[4], v[5]);
    p.w = packtrunc(v[6], v[7]);
    return p;
}

// ---------------------------------------------------------------------------
// Stage one 64x128 A-tile (period p) into swizzled LDS — 512-thread map.
// Row stride 128 ushort; 16B blocks, stored blk = i ^ (row&15).
// Thread covers row rowA = tid>>3, blocks i = colq*2, colq*2+1 (colq = tid&7).
//   spline period: 2 x-elems = the preloaded float2 xsp
//   silu  period: 16 consecutive x
// ---------------------------------------------------------------------------
__device__ __forceinline__ void stageA128(unsigned short* dst, const float* xrow,
                                          int rowA, int colq, int p, float2 xsp)
{
    unsigned short* arow = dst + rowA * 128;
    if (p < NSPER) {
        const float xv[2] = {xsp.x, xsp.y};
        #pragma unroll
        for (int e = 0; e < 2; ++e) {
            const uint4 pk = basis_pack(xv[e]);
            const int blk = (colq * 2 + e) ^ (rowA & 15);
            *reinterpret_cast<uint4*>(arow + blk * 8) = pk;
        }
    } else {
        const float* xs = xrow + (p - NSPER) * 128 + colq * 16;
        #pragma unroll
        for (int e = 0; e < 2; ++e) {
            const float4 a0 = *reinterpret_cast<const float4*>(xs + e * 8);
            const float4 a1 = *reinterpret_cast<const float4*>(xs + e * 8 + 4);
            const float f[8] = {a0.x, a0.y, a0.z, a0.w, a1.x, a1.y, a1.z, a1.w};
            float s[8];
            #pragma unroll
            for (int j = 0; j < 8; ++j)
                s[j] = f[j] * __builtin_amdgcn_rcpf(
                    1.0f + __builtin_amdgcn_exp2f(-f[j] * L2E));
            uint4 pk;
            pk.x = packtrunc(s[0], s[1]);
            pk.y = packtrunc(s[2], s[3]);
            pk.z = packtrunc(s[4], s[5]);
            pk.w = packtrunc(s[6], s[7]);
            const int blk = (colq * 2 + e) ^ (rowA & 15);
            *reinterpret_cast<uint4*>(arow + blk * 8) = pk;
        }
    }
}

// B fragment load for one 64-k half-period (kt): 4 nt x 2 s
template<bool PREP>
__device__ __forceinline__ void load_bfrags(short8 dst[4][2], const short8* __restrict__ Bf,
                                            const size_t* bbase, int kt,
                                            const float* __restrict__ sw,
                                            const float* __restrict__ bw,
                                            int col0, int lane)
{
    if (kt >= NKT) return;
    if (PREP) {
        #pragma unroll
        for (int nt = 0; nt < 4; ++nt)
            #pragma unroll
            for (int s = 0; s < 2; ++s)
                dst[nt][s] = Bf[bbase[nt] + (size_t)(kt * 2 + s) * 64];
    } else {
        const int mn = lane & 15, q = lane >> 4;
        #pragma unroll
        for (int nt = 0; nt < 4; ++nt) {
            const int n = col0 + nt * 16 + mn;
            #pragma unroll
            for (int s = 0; s < 2; ++s) {
                short8 v;
                #pragma unroll
                for (int j = 0; j < 8; ++j) {
                    const int k = (kt * 2 + s) * 32 + q * 8 + j;
                    const float val = (k < K_SPLINE)
                        ? sw[(size_t)k * OUT_DIM + n]
                        : bw[(size_t)n * IN_DIM + (k - K_SPLINE)];
                    v[j] = (short)f2bf(val);
                }
                dst[nt][s] = v;
            }
        }
    }
}

// ---------------------------------------------------------------------------
// Fused KAN — R0 machinery, merged col-halves: 256 blocks x 8 waves.
//   Block tile 64x512 (one block per row-group -> A staged ONCE, not twice).
//   Wave tile 64x64; A LDS dbuf 2x16KB; B reg dbuf at 64-k half granularity.
//   One barrier per 128-k period (36 total). Inner loop identical to R0.
// ---------------------------------------------------------------------------
template<bool PREP>
__global__ __launch_bounds__(512, 2) void kan_kernel(
    const float* __restrict__ x,
    const unsigned short* __restrict__ Btf,
    const float* __restrict__ sw,
    const float* __restrict__ bw,
    const float* __restrict__ bias,
    float* __restrict__ out)
{
    __shared__ unsigned short Als[2][64 * 128];   // 2 x 16 KB

    const int tid  = threadIdx.x;
    const int wn   = tid >> 6;          // wave -> 64-col group (0..7)
    const int lane = tid & 63;
    const int q    = lane >> 4;
    const int mn   = lane & 15;
    const int bid  = blockIdx.x;
    const int row0 = bid * 64;
    const int col0 = wn * 64;

    const int rowA = tid >> 3;          // 0..63
    const int colq = tid & 7;           // 0..7
    const float* xrow = x + (size_t)(row0 + rowA) * IN_DIM;

    size_t bbase[4];
    #pragma unroll
    for (int nt = 0; nt < 4; ++nt)
        bbase[nt] = (size_t)(((col0 >> 4) + nt) * NKTILE) * 64 + lane;
    const short8* Bf = reinterpret_cast<const short8*>(Btf);

    floatx4 acc[4][4];
    #pragma unroll
    for (int i = 0; i < 4; ++i)
        #pragma unroll
        for (int j = 0; j < 4; ++j)
            acc[i][j] = (floatx4){0.f, 0.f, 0.f, 0.f};

    short8 bb[2][4][2];   // B dbuf, literal-indexed via unrolled hh

    // prologue: spline x for p=0, stage p=0, B for kt=0; prefetch x for p=1
    float2 xsp = *reinterpret_cast<const float2*>(xrow + colq * 2);
    stageA128(&Als[0][0], xrow, rowA, colq, 0, xsp);
    load_bfrags<PREP>(bb[0], Bf, bbase, 0, sw, bw, col0, lane);
    xsp = *reinterpret_cast<const float2*>(xrow + 16 + colq * 2);
    __syncthreads();

    for (int p = 0; p < NPER; ++p) {
        const unsigned short* Acur = &Als[p & 1][0];
        unsigned short*       Anxt = &Als[(p & 1) ^ 1][0];

        // B for second half of this period (kt = 2p+1)
        load_bfrags<PREP>(bb[1], Bf, bbase, 2 * p + 1, sw, bw, col0, lane);

        // stage A for period p+1 (overlaps this period's MFMA)
        if (p + 1 < NPER) {
            stageA128(Anxt, xrow, rowA, colq, p + 1, xsp);
            if (p + 2 < NSPER)
                xsp = *reinterpret_cast<const float2*>(
                    xrow + (p + 2) * 16 + colq * 2);
        }

        #pragma unroll
        for (int hh = 0; hh < 2; ++hh) {           // literal B-dbuf index
            #pragma unroll
            for (int s = 0; s < 2; ++s) {
                const int st = hh * 2 + s;
                short8 af[4];
                #pragma unroll
                for (int mt = 0; mt < 4; ++mt) {
                    const int r = mt * 16 + mn;
                    af[mt] = *reinterpret_cast<const short8*>(
                        Acur + r * 128 + (((st * 4 + q) ^ (r & 15)) * 8));
                }
                #pragma unroll
                for (int mt = 0; mt < 4; ++mt)
                    #pragma unroll
                    for (int nt = 0; nt < 4; ++nt)
                        acc[mt][nt] = __builtin_amdgcn_mfma_f32_16x16x32_bf16(
                            af[mt], bb[hh][nt][s], acc[mt][nt], 0, 0, 0);
            }
            // after consuming bb[0], prefetch first half of NEXT period into bb[0]
            if (hh == 0)
                load_bfrags<PREP>(bb[0], Bf, bbase, 2 * p + 2, sw, bw, col0, lane);
        }
        __syncthreads();
    }

    // epilogue: + bias, store fp32
    #pragma unroll
    for (int nt = 0; nt < 4; ++nt) {
        const int col = col0 + nt * 16 + mn;
        const float bv = bias[col];
        #pragma unroll
        for (int mt = 0; mt < 4; ++mt) {
            const int rb = row0 + mt * 16 + q * 4;
            #pragma unroll
            for (int e = 0; e < 4; ++e)
                out[(size_t)(rb + e) * OUT_DIM + col] = acc[mt][nt][e] + bv;
        }
    }
}

extern "C" void kernel_launch(void* const* d_in, const int* in_sizes, int n_in,
                              void* d_out, int out_size, void* d_ws, size_t ws_size,
                              hipStream_t stream)
{
    const float* x    = (const float*)d_in[0];
    // d_in[1] = grid (linspace(-2,2,8)) — folded into constants
    const float* sw   = (const float*)d_in[2];
    const float* bw   = (const float*)d_in[3];
    const float* bias = (const float*)d_in[4];
    float* out = (float*)d_out;

    const size_t bt_bytes = (size_t)OUT_DIM * K_TOT * sizeof(unsigned short);
    if (ws_size >= bt_bytes) {
        unsigned short* Btf = (unsigned short*)d_ws;
        prep_kernel<<<dim3(NKTILE / 4, OUT_DIM / 16), 256, 0, stream>>>(sw, bw, Btf);
        kan_kernel<true><<<dim3(256), 512, 0, stream>>>(
            x, Btf, sw, bw, bias, out);
    } else {
        kan_kernel<false><<<dim3(256), 512, 0, stream>>>(
            x, nullptr, sw, bw, bias, out);
    }
}